// Round 17
// baseline (177.523 us; speedup 1.0000x reference)
//
#include <hip/hip_runtime.h>
#include <hip/hip_bf16.h>
#include <stdint.h>

// out = tril(Q K^T) * scale @ V  (no softmax), Q/K/V = x @ W^T + b
// B=4, N=2048, D=1024, f32 in/out; bf16 MFMA, f32 accum.
// QKV: 256x384 tile, BK=32, 512 thr, depth-2 counted-vmcnt ring, 120 KiB LDS,
//      grid=256 blocks = exactly 1 round at 1 block/CU.
// scores/PV: R14 verbatim (128x256, depth-2 ring, 72 KiB, 2 blocks/CU).

typedef __attribute__((ext_vector_type(4))) float f32x4;
typedef __attribute__((ext_vector_type(8))) short bf16x8s;
typedef __attribute__((ext_vector_type(4))) short bf16x4s;

__device__ __forceinline__ short f2bf(float f) {
  union { float f; unsigned u; } v; v.f = f;
  return (short)((v.u + 0x7FFFu + ((v.u >> 16) & 1u)) >> 16);  // RNE
}

// ---------------- fused cast f32 -> bf16 ----------------
__global__ void cast_all(const float* __restrict__ x, const float* __restrict__ wq,
                         const float* __restrict__ wk, const float* __restrict__ wv,
                         short* __restrict__ xb, short* __restrict__ wcat) {
  const int n4x = 1 << 21;
  const int n4w = 1 << 18;
  const int total = n4x + 3 * n4w;
  int idx = blockIdx.x * blockDim.x + threadIdx.x;
  int stride = gridDim.x * blockDim.x;
  for (int i = idx; i < total; i += stride) {
    f32x4 v;
    short* dst;
    if (i < n4x) {
      v = ((const f32x4*)x)[i];
      dst = xb + (size_t)i * 4;
    } else {
      int j = i - n4x;
      int sel = j >> 18, off = j & (n4w - 1);
      const float* src = (sel == 0) ? wq : (sel == 1) ? wk : wv;
      v = ((const f32x4*)src)[off];
      dst = wcat + (size_t)j * 4;
    }
    bf16x4s o;
    o[0] = f2bf(v[0]); o[1] = f2bf(v[1]); o[2] = f2bf(v[2]); o[3] = f2bf(v[3]);
    *(bf16x4s*)dst = o;
  }
}

// ---------------- staging / fragment-read machinery (512 threads) ----------------
// Swizzle: 16B-granule g ^= (row>>1)&3; inverse on global src, applied on ds_read.
// rows-per-e = 128 (multiple of 8) -> (row>>1)&3 == (lane>>3)&3 for every e.

// stage 256 rows x 32 cols (16KB): 2 gload_lds(16B)/thread
#define STAGE2(gp, ld_, kelem, slot)                                                  \
  {                                                                                   \
    const int ksrc_ = (((lane & 3) ^ ((lane >> 3) & 3)) << 3);                        \
    _Pragma("unroll") for (int e_ = 0; e_ < 2; ++e_) {                                \
      int row_ = e_ * 128 + wid * 16 + (lane >> 2);                                   \
      const short* src_ = (gp) + (size_t)row_ * (ld_) + (kelem) + ksrc_;              \
      __builtin_amdgcn_global_load_lds(                                               \
          (const __attribute__((address_space(1))) void*)src_,                        \
          (__attribute__((address_space(3))) void*)((slot) + e_ * 4096 + wid * 512),  \
          16, 0, 0);                                                                  \
    }                                                                                 \
  }

// stage 384 rows x 32 cols (24KB): 3 gload_lds(16B)/thread
#define STAGE3(gp, ld_, kelem, slot)                                                  \
  {                                                                                   \
    const int ksrc_ = (((lane & 3) ^ ((lane >> 3) & 3)) << 3);                        \
    _Pragma("unroll") for (int e_ = 0; e_ < 3; ++e_) {                                \
      int row_ = e_ * 128 + wid * 16 + (lane >> 2);                                   \
      const short* src_ = (gp) + (size_t)row_ * (ld_) + (kelem) + ksrc_;              \
      __builtin_amdgcn_global_load_lds(                                               \
          (const __attribute__((address_space(1))) void*)src_,                        \
          (__attribute__((address_space(3))) void*)((slot) + e_ * 4096 + wid * 512),  \
          16, 0, 0);                                                                  \
    }                                                                                 \
  }

// stage 128 rows x 32 cols (8KB): 1 gload_lds(16B)/thread
#define STAGE1(gp, ld_, kelem, slot)                                                  \
  {                                                                                   \
    const int ksrc_ = (((lane & 3) ^ ((lane >> 3) & 3)) << 3);                        \
    int row_ = wid * 16 + (lane >> 2);                                                \
    const short* src_ = (gp) + (size_t)row_ * (ld_) + (kelem) + ksrc_;                \
    __builtin_amdgcn_global_load_lds(                                                 \
        (const __attribute__((address_space(1))) void*)src_,                          \
        (__attribute__((address_space(3))) void*)((slot) + wid * 512), 16, 0, 0);     \
  }

#define LDSF(slot, row) \
  (*(const bf16x8s*)&(slot)[(row) * 32 + ((kq ^ (((row) >> 1) & 3)) << 3)])

// =========== QKV: 256x384 / BK=32 / depth-2 ring, 1 block/CU, 1 round ===========
// 8 waves (2m x 4n), wave output 128x96, acc[8][6].
// LDS: A slots 8192 shorts @ s*8192 (s<3); B slots 12288 shorts @ 24576+s*12288.
__global__ __launch_bounds__(512, 1) void k_qkv(
    const short* __restrict__ A, const short* __restrict__ Bm,
    const float* __restrict__ bq, const float* __restrict__ bk,
    const float* __restrict__ bv, short* __restrict__ Qb,
    short* __restrict__ Kb, short* __restrict__ Vt) {
  const int NTv = 32;
  int id = blockIdx.x;                  // 256 blocks; XCD-bijective (256 = 8*32)
  int swz = (id & 7) * 32 + (id >> 3);
  const int tx = swz & 7, ty = swz >> 3;   // ty: 256-row A tile, tx: 384-row B tile
  const short* Ap = A + (size_t)(ty * 256) * 1024;
  const short* Bp = Bm + (size_t)(tx * 384) * 1024;

  __shared__ short lds[61440];  // 120 KiB

  const int tid = threadIdx.x;
  const int wid = tid >> 6, lane = tid & 63;
  const int wm = wid >> 2, wn = wid & 3;   // 2m x 4n waves, 128x96 out each
  const int kq = lane >> 4, r16 = lane & 15;

  f32x4 acc[8][6];
#pragma unroll
  for (int i = 0; i < 8; ++i)
#pragma unroll
    for (int j = 0; j < 6; ++j) { f32x4 z = {0.f, 0.f, 0.f, 0.f}; acc[i][j] = z; }

  // prologue: stage tiles 0 and 1 (slots 0, 1); wait tile 0 (5 newest in flight)
  STAGE2(Ap, 1024, 0, (lds + 0));
  STAGE3(Bp, 1024, 0, (lds + 24576));
  STAGE2(Ap, 1024, 32, (lds + 8192));
  STAGE3(Bp, 1024, 32, (lds + 24576 + 12288));
  asm volatile("s_waitcnt vmcnt(5)" ::: "memory");
  __builtin_amdgcn_s_barrier();

  int cs = 0;  // slot of tile T
  for (int T = 0; T < NTv; ++T) {
    int ns = cs + 2; if (ns >= 3) ns -= 3;   // slot of tile T+2
    if (T + 2 < NTv) {
      STAGE2(Ap, 1024, (T + 2) * 32, (lds + ns * 8192));
      STAGE3(Bp, 1024, (T + 2) * 32, (lds + 24576 + ns * 12288));
    }
    short* curA = lds + cs * 8192;
    short* curB = lds + 24576 + cs * 12288;
    bf16x8s a_[8], b_[6];
#pragma unroll
    for (int mi = 0; mi < 8; ++mi)
      a_[mi] = LDSF(curA, wm * 128 + mi * 16 + r16);
#pragma unroll
    for (int nj = 0; nj < 6; ++nj)
      b_[nj] = LDSF(curB, wn * 96 + nj * 16 + r16);
    asm volatile("s_waitcnt lgkmcnt(0)" ::: "memory");
    __builtin_amdgcn_s_setprio(1);
#pragma unroll
    for (int mi = 0; mi < 8; ++mi)
#pragma unroll
      for (int nj = 0; nj < 6; ++nj)
        acc[mi][nj] = __builtin_amdgcn_mfma_f32_16x16x32_bf16(a_[mi], b_[nj], acc[mi][nj], 0, 0, 0);
    __builtin_amdgcn_s_setprio(0);
    if (T < NTv - 2) {
      asm volatile("s_waitcnt vmcnt(5)" ::: "memory");  // tile T+1 landed
    } else {
      asm volatile("s_waitcnt vmcnt(0)" ::: "memory");  // tail drain
    }
    __builtin_amdgcn_s_barrier();
    cs = (cs + 1 == 3) ? 0 : cs + 1;
  }

  // ---- epilogue: per-fragment segment routing (384 cols span Q/K/V bounds) ----
#pragma unroll
  for (int mf = 0; mf < 8; ++mf) {
    int rowg = ty * 256 + wm * 128 + mf * 16 + kq * 4;  // 4 consecutive rows
#pragma unroll
    for (int nj = 0; nj < 6; ++nj) {
      int colg = tx * 384 + wn * 96 + nj * 16 + r16;    // 0..3071
      int seg = colg >> 10;                             // 0:Q 1:K 2:V
      int col = colg & 1023;
      if (seg < 2) {
        short* Cb = (seg == 0) ? Qb : Kb;
        float bvv = ((seg == 0) ? bq : bk)[col];
#pragma unroll
        for (int rr = 0; rr < 4; ++rr)
          Cb[(size_t)(rowg + rr) * 1024 + col] = f2bf(acc[mf][nj][rr] + bvv);
      } else {
        int b = rowg >> 11, n0 = rowg & 2047;
        long long base = (long long)b * (1024LL * 2048LL);
        float bvv = bv[col];
        bf16x4s o;
#pragma unroll
        for (int rr = 0; rr < 4; ++rr) o[rr] = f2bf(acc[mf][nj][rr] + bvv);
        *(bf16x4s*)&Vt[base + (long long)col * 2048 + n0] = o;
      }
    }
  }
}

// ===== scores / PV: R14 verbatim (128x256, 512 thr, depth-2 ring) =====
template <int MODE>
__device__ __forceinline__ void gemm_body(
    const short* __restrict__ A, const short* __restrict__ Bm,
    short* __restrict__ Sb, float* __restrict__ O, float scale) {
  const int ld = (MODE == 3) ? 2048 : 1024;
  int tx, ty, NTv;
  const short *Abase, *Bbase;
  long long bz = blockIdx.z;
  if (MODE == 2) {
    int id = blockIdx.x;                 // 72 tiles (128q x 256k); 72 = 8*9
    int ti = (id & 7) * 9 + (id >> 3);
    int qt = 0, c = 0;
    while (c + (qt / 2 + 1) <= ti) { c += qt / 2 + 1; ++qt; }
    ty = qt; tx = ti - c;
    Abase = A + bz * (2048LL * 1024LL);
    Bbase = Bm + bz * (2048LL * 1024LL);
    NTv = 32;
  } else {
    int id = blockIdx.x;                 // 64 tiles: 16 q-tiles x 4 e-tiles
    tx = id & 3;
    ty = 15 - (id >> 2);                 // longest-first
    Abase = A + bz * (2048LL * 2048LL);
    Bbase = Bm + bz * (1024LL * 2048LL);
    NTv = (ty + 1) * 4;                  // Kend = (ty+1)*128
  }
  const short* Ap = Abase + (size_t)(ty * 128) * ld;
  const short* Bp = Bbase + (size_t)(tx * 256) * ld;

  __shared__ short lds[36864];  // 72 KiB

  const int tid = threadIdx.x;
  const int wid = tid >> 6, lane = tid & 63;
  const int wm = wid >> 2, wn = wid & 3;   // 2 x 4 waves, 64x64 out each
  const int kq = lane >> 4, r16 = lane & 15;

  f32x4 acc[4][4];
#pragma unroll
  for (int i = 0; i < 4; ++i)
#pragma unroll
    for (int j = 0; j < 4; ++j) { f32x4 z = {0.f, 0.f, 0.f, 0.f}; acc[i][j] = z; }

  STAGE1(Ap, ld, 0, (lds + 0));
  STAGE2(Bp, ld, 0, (lds + 12288));
  STAGE1(Ap, ld, 32, (lds + 4096));
  STAGE2(Bp, ld, 32, (lds + 12288 + 8192));
  asm volatile("s_waitcnt vmcnt(3)" ::: "memory");
  __builtin_amdgcn_s_barrier();

  int cs = 0;
  for (int T = 0; T < NTv; ++T) {
    int ns = cs + 2; if (ns >= 3) ns -= 3;
    if (T + 2 < NTv) {
      STAGE1(Ap, ld, (T + 2) * 32, (lds + ns * 4096));
      STAGE2(Bp, ld, (T + 2) * 32, (lds + 12288 + ns * 8192));
    }
    short* curA = lds + cs * 4096;
    short* curB = lds + 12288 + cs * 8192;
    bf16x8s a_[4], b_[4];
#pragma unroll
    for (int mi = 0; mi < 4; ++mi)
      a_[mi] = LDSF(curA, wm * 64 + mi * 16 + r16);
#pragma unroll
    for (int nj = 0; nj < 4; ++nj)
      b_[nj] = LDSF(curB, wn * 64 + nj * 16 + r16);
    asm volatile("s_waitcnt lgkmcnt(0)" ::: "memory");
    __builtin_amdgcn_s_setprio(1);
#pragma unroll
    for (int mi = 0; mi < 4; ++mi)
#pragma unroll
      for (int nj = 0; nj < 4; ++nj)
        acc[mi][nj] = __builtin_amdgcn_mfma_f32_16x16x32_bf16(a_[mi], b_[nj], acc[mi][nj], 0, 0, 0);
    __builtin_amdgcn_s_setprio(0);
    if (T < NTv - 2) {
      asm volatile("s_waitcnt vmcnt(3)" ::: "memory");
    } else {
      asm volatile("s_waitcnt vmcnt(0)" ::: "memory");
    }
    __builtin_amdgcn_s_barrier();
    cs = (cs + 1 == 3) ? 0 : cs + 1;
  }

  const int rowt0 = ty * 128 + wm * 64;
  const int colt0 = tx * 256 + wn * 64;
  if (MODE == 2) {
    short* Cb = Sb + bz * (2048LL * 2048LL);
#pragma unroll
    for (int mf = 0; mf < 4; ++mf) {
#pragma unroll
      for (int nj = 0; nj < 4; ++nj) {
        int col = colt0 + nj * 16 + r16;
#pragma unroll
        for (int rr = 0; rr < 4; ++rr) {
          int row = rowt0 + mf * 16 + kq * 4 + rr;
          float v = (col <= row) ? acc[mf][nj][rr] * scale : 0.0f;
          Cb[(size_t)row * 2048 + col] = f2bf(v);
        }
      }
    }
  } else {
    float* Cb = O + bz * (2048LL * 1024LL);
#pragma unroll
    for (int mf = 0; mf < 4; ++mf) {
#pragma unroll
      for (int nj = 0; nj < 4; ++nj) {
        int col = colt0 + nj * 16 + r16;
#pragma unroll
        for (int rr = 0; rr < 4; ++rr) {
          int row = rowt0 + mf * 16 + kq * 4 + rr;
          Cb[(size_t)row * 1024 + col] = acc[mf][nj][rr];
        }
      }
    }
  }
}

__global__ __launch_bounds__(512, 4) void k_scores(
    const short* __restrict__ Q, const short* __restrict__ K,
    short* __restrict__ Sb, float scale) {
  gemm_body<2>(Q, K, Sb, nullptr, scale);
}

__global__ __launch_bounds__(512, 4) void k_pv(
    const short* __restrict__ S, const short* __restrict__ Vt,
    float* __restrict__ O) {
  gemm_body<3>(S, Vt, nullptr, O, 1.0f);
}

extern "C" void kernel_launch(void* const* d_in, const int* in_sizes, int n_in,
                              void* d_out, int out_size, void* d_ws, size_t ws_size,
                              hipStream_t stream) {
  const float* x  = (const float*)d_in[0];
  const float* Wq = (const float*)d_in[1];
  const float* bq = (const float*)d_in[2];
  const float* Wk = (const float*)d_in[3];
  const float* bk = (const float*)d_in[4];
  const float* Wv = (const float*)d_in[5];
  const float* bv = (const float*)d_in[6];

  const int B = 4;
  const long long MB = 1LL << 20;

  char* ws = (char*)d_ws;
  short* Qb   = (short*)(ws + 0 * MB);   // 16 MB bf16 Q [8192,1024]
  short* Kb   = (short*)(ws + 16 * MB);  // 16 MB bf16 K
  short* Vt   = (short*)(ws + 32 * MB);  // 16 MB bf16 V^T [4][1024][2048]
  short* xb   = (short*)(ws + 48 * MB);  // 16 MB bf16 x     (dead after QKV)
  short* Wcat = (short*)(ws + 64 * MB);  // 6 MB  bf16 [Wq;Wk;Wv] (dead after QKV)
  short* Sb   = (short*)(ws + 48 * MB);  // 32 MB scores, reuses xb/Wcat

  // 1. fused casts
  cast_all<<<2048, 256, 0, stream>>>(x, Wq, Wk, Wv, xb, Wcat);

  // 2. fused QKV projection: [8192,3072] = xb @ Wcat^T ; 256 blocks = 1 round
  k_qkv<<<256, 512, 0, stream>>>(xb, Wcat, bq, bk, bv, Qb, Kb, Vt);

  // 3. scores: per batch S = tril(Q K^T) / 32, 72 (128x256) tiles x 4 batches
  dim3 g2(72, 1, B);
  k_scores<<<g2, 512, 0, stream>>>(Qb, Kb, Sb, 0.03125f);

  // 4. PV: per batch O = S @ Vt^T, causal K-extent, longest-first
  dim3 g3(64, 1, B);
  k_pv<<<g3, 512, 0, stream>>>(Sb, Vt, (float*)d_out);
}

// Round 18
// 146.061 us; speedup vs baseline: 1.2154x; 1.2154x over previous
//
#include <hip/hip_runtime.h>
#include <hip/hip_bf16.h>
#include <stdint.h>

// out = tril(Q K^T) * scale @ V  (no softmax), Q/K/V = x @ W^T + b
// B=4, N=2048, D=1024, f32 in/out; bf16 MFMA, f32 accum.
// All GEMMs: 128x256 tile, BK=32, 512 thr / 8 waves, depth-2 counted-vmcnt
// pipeline, 3-slot ring, 72 KiB LDS, 2 blocks/CU.  (R9/R14 configuration - best.)

typedef __attribute__((ext_vector_type(4))) float f32x4;
typedef __attribute__((ext_vector_type(8))) short bf16x8s;
typedef __attribute__((ext_vector_type(4))) short bf16x4s;

__device__ __forceinline__ short f2bf(float f) {
  union { float f; unsigned u; } v; v.f = f;
  return (short)((v.u + 0x7FFFu + ((v.u >> 16) & 1u)) >> 16);  // RNE
}

// ---------------- fused cast f32 -> bf16 ----------------
__global__ void cast_all(const float* __restrict__ x, const float* __restrict__ wq,
                         const float* __restrict__ wk, const float* __restrict__ wv,
                         short* __restrict__ xb, short* __restrict__ wcat) {
  const int n4x = 1 << 21;
  const int n4w = 1 << 18;
  const int total = n4x + 3 * n4w;
  int idx = blockIdx.x * blockDim.x + threadIdx.x;
  int stride = gridDim.x * blockDim.x;
  for (int i = idx; i < total; i += stride) {
    f32x4 v;
    short* dst;
    if (i < n4x) {
      v = ((const f32x4*)x)[i];
      dst = xb + (size_t)i * 4;
    } else {
      int j = i - n4x;
      int sel = j >> 18, off = j & (n4w - 1);
      const float* src = (sel == 0) ? wq : (sel == 1) ? wk : wv;
      v = ((const f32x4*)src)[off];
      dst = wcat + (size_t)j * 4;
    }
    bf16x4s o;
    o[0] = f2bf(v[0]); o[1] = f2bf(v[1]); o[2] = f2bf(v[2]); o[3] = f2bf(v[3]);
    *(bf16x4s*)dst = o;
  }
}

// ---------------- staging / fragment-read machinery ----------------
// Swizzle: 16B-slot s = ks ^ ((row>>1)&3); inverse on global src, applied on ds_read.

// stage 256 rows x 32 cols (16KB): 2 gload_lds(16B)/thread, linear LDS dest
#define STAGE2(gp, ld_, kelem, slot)                                                  \
  {                                                                                   \
    const int ksrc_ = (((lane & 3) ^ ((lane >> 3) & 3)) << 3);                        \
    _Pragma("unroll") for (int e_ = 0; e_ < 2; ++e_) {                                \
      int row_ = e_ * 128 + wid * 16 + (lane >> 2);                                   \
      const short* src_ = (gp) + (size_t)row_ * (ld_) + (kelem) + ksrc_;              \
      __builtin_amdgcn_global_load_lds(                                               \
          (const __attribute__((address_space(1))) void*)src_,                        \
          (__attribute__((address_space(3))) void*)((slot) + e_ * 4096 + wid * 512),  \
          16, 0, 0);                                                                  \
    }                                                                                 \
  }

// stage 128 rows x 32 cols (8KB): 1 gload_lds(16B)/thread
#define STAGE1(gp, ld_, kelem, slot)                                                  \
  {                                                                                   \
    const int ksrc_ = (((lane & 3) ^ ((lane >> 3) & 3)) << 3);                        \
    int row_ = wid * 16 + (lane >> 2);                                                \
    const short* src_ = (gp) + (size_t)row_ * (ld_) + (kelem) + ksrc_;                \
    __builtin_amdgcn_global_load_lds(                                                 \
        (const __attribute__((address_space(1))) void*)src_,                          \
        (__attribute__((address_space(3))) void*)((slot) + wid * 512), 16, 0, 0);     \
  }

#define LDSF(slot, row) \
  (*(const bf16x8s*)&(slot)[(row) * 32 + ((kq ^ (((row) >> 1) & 3)) << 3)])

// ========== 128x256 / BK=32 / depth-2 counted-vmcnt pipelined GEMM ==========
// 512 threads = 8 waves (2m x 4n), 64x64 out/wave, acc[4][4].
// LDS: 3 x (A 4096 + B 8192 shorts) = 72 KiB -> 2 blocks/CU.
// Tile T: STAGE(T+2) -> ds_read(T) -> lgkm -> MFMA -> vmcnt(3) [T+1 landed] -> bar.

// MODE 0: QKV. A=xb[8192,1024], B=Wcat[3072,1024]; epilogue seg -> Qb/Kb/Vt.
// MODE 2: scores. per-batch triangular; epilogue mask+scale -> Sb (bf16).
// MODE 3: PV. A=Sb[2048,2048], B=Vt[1024,2048]; variable NT=(ty+1)*4; f32 -> O.
template <int MODE>
__device__ __forceinline__ void gemm_body(
    const short* __restrict__ A, const short* __restrict__ Bm,
    const float* __restrict__ bq, const float* __restrict__ bk,
    const float* __restrict__ bv, short* __restrict__ Qb,
    short* __restrict__ Kb, short* __restrict__ Vt,
    short* __restrict__ Sb, float* __restrict__ O, float scale) {
  const int ld = (MODE == 3) ? 2048 : 1024;
  int tx, ty, NTv;
  const short *Abase, *Bbase;
  long long bz = 0;
  if (MODE == 0) {
    int id = blockIdx.x;                 // 768 blocks; XCD-bijective (768 = 8*96)
    int swz = (id & 7) * 96 + (id >> 3);
    tx = swz % 12; ty = swz / 12;        // ty: 128-row A tile, tx: 256-row B tile
    Abase = A; Bbase = Bm;
    NTv = 32;
  } else if (MODE == 2) {
    bz = blockIdx.z;
    int id = blockIdx.x;                 // 72 tiles (128q x 256k); 72 = 8*9
    int ti = (id & 7) * 9 + (id >> 3);
    int qt = 0, c = 0;
    while (c + (qt / 2 + 1) <= ti) { c += qt / 2 + 1; ++qt; }
    ty = qt; tx = ti - c;
    Abase = A + bz * (2048LL * 1024LL);
    Bbase = Bm + bz * (2048LL * 1024LL);
    NTv = 32;
  } else {
    bz = blockIdx.z;
    int id = blockIdx.x;                 // 64 tiles: 16 q-tiles x 4 e-tiles
    tx = id & 3;
    ty = 15 - (id >> 2);                 // longest-first
    Abase = A + bz * (2048LL * 2048LL);
    Bbase = Bm + bz * (1024LL * 2048LL);
    NTv = (ty + 1) * 4;                  // Kend = (ty+1)*128
  }
  const short* Ap = Abase + (size_t)(ty * 128) * ld;
  const short* Bp = Bbase + (size_t)(tx * 256) * ld;

  __shared__ short lds[36864];  // 72 KiB: A slots @ s*4096 (s<3), B @ 12288 + s*8192

  const int tid = threadIdx.x;
  const int wid = tid >> 6, lane = tid & 63;
  const int wm = wid >> 2, wn = wid & 3;   // 2 x 4 waves, 64x64 out each
  const int kq = lane >> 4, r16 = lane & 15;

  f32x4 acc[4][4];
#pragma unroll
  for (int i = 0; i < 4; ++i)
#pragma unroll
    for (int j = 0; j < 4; ++j) { f32x4 z = {0.f, 0.f, 0.f, 0.f}; acc[i][j] = z; }

  // prologue: stage tiles 0 and 1 (slots 0, 1); wait tile 0 (3 newest in flight)
  STAGE1(Ap, ld, 0, (lds + 0));
  STAGE2(Bp, ld, 0, (lds + 12288));
  STAGE1(Ap, ld, 32, (lds + 4096));
  STAGE2(Bp, ld, 32, (lds + 12288 + 8192));
  asm volatile("s_waitcnt vmcnt(3)" ::: "memory");
  __builtin_amdgcn_s_barrier();

  int cs = 0;  // slot of tile T
  for (int T = 0; T < NTv; ++T) {
    int ns = cs + 2; if (ns >= 3) ns -= 3;   // slot of tile T+2
    if (T + 2 < NTv) {
      STAGE1(Ap, ld, (T + 2) * 32, (lds + ns * 4096));
      STAGE2(Bp, ld, (T + 2) * 32, (lds + 12288 + ns * 8192));
    }
    short* curA = lds + cs * 4096;
    short* curB = lds + 12288 + cs * 8192;
    bf16x8s a_[4], b_[4];
#pragma unroll
    for (int mi = 0; mi < 4; ++mi)
      a_[mi] = LDSF(curA, wm * 64 + mi * 16 + r16);
#pragma unroll
    for (int nj = 0; nj < 4; ++nj)
      b_[nj] = LDSF(curB, wn * 64 + nj * 16 + r16);
    asm volatile("s_waitcnt lgkmcnt(0)" ::: "memory");
    __builtin_amdgcn_s_setprio(1);
#pragma unroll
    for (int mi = 0; mi < 4; ++mi)
#pragma unroll
      for (int nj = 0; nj < 4; ++nj)
        acc[mi][nj] = __builtin_amdgcn_mfma_f32_16x16x32_bf16(a_[mi], b_[nj], acc[mi][nj], 0, 0, 0);
    __builtin_amdgcn_s_setprio(0);
    if (T < NTv - 2) {
      asm volatile("s_waitcnt vmcnt(3)" ::: "memory");  // tile T+1 landed
    } else {
      asm volatile("s_waitcnt vmcnt(0)" ::: "memory");  // tail drain
    }
    __builtin_amdgcn_s_barrier();
    cs = (cs + 1 == 3) ? 0 : cs + 1;
  }

  // ---- epilogue ----
  const int rowt0 = ty * 128 + wm * 64;
  if (MODE == 0) {
    const int seg = tx >> 2;                       // 0:Q 1:K 2:V
    const int colseg0 = (tx & 3) * 256 + wn * 64;
    if (seg < 2) {
      short* Cb = (seg == 0) ? Qb : Kb;
      const float* bias = (seg == 0) ? bq : bk;
#pragma unroll
      for (int mf = 0; mf < 4; ++mf) {
#pragma unroll
        for (int nj = 0; nj < 4; ++nj) {
          int col = colseg0 + nj * 16 + r16;
          float bvv = bias[col];
#pragma unroll
          for (int rr = 0; rr < 4; ++rr) {
            int row = rowt0 + mf * 16 + kq * 4 + rr;
            Cb[(size_t)row * 1024 + col] = f2bf(acc[mf][nj][rr] + bvv);
          }
        }
      }
    } else {
      // Vt[b][e][n]
#pragma unroll
      for (int mf = 0; mf < 4; ++mf) {
        int rowg = rowt0 + mf * 16 + kq * 4;
        int b = rowg >> 11, n0 = rowg & 2047;
        long long base = (long long)b * (1024LL * 2048LL);
#pragma unroll
        for (int nj = 0; nj < 4; ++nj) {
          int col = colseg0 + nj * 16 + r16;
          float bvv = bv[col];
          bf16x4s o;
#pragma unroll
          for (int rr = 0; rr < 4; ++rr) o[rr] = f2bf(acc[mf][nj][rr] + bvv);
          *(bf16x4s*)&Vt[base + (long long)col * 2048 + n0] = o;
        }
      }
    }
  } else if (MODE == 2) {
    short* Cb = Sb + bz * (2048LL * 2048LL);
    const int colt0 = tx * 256 + wn * 64;
#pragma unroll
    for (int mf = 0; mf < 4; ++mf) {
#pragma unroll
      for (int nj = 0; nj < 4; ++nj) {
        int col = colt0 + nj * 16 + r16;
#pragma unroll
        for (int rr = 0; rr < 4; ++rr) {
          int row = rowt0 + mf * 16 + kq * 4 + rr;
          float v = (col <= row) ? acc[mf][nj][rr] * scale : 0.0f;
          Cb[(size_t)row * 2048 + col] = f2bf(v);
        }
      }
    }
  } else {
    float* Cb = O + bz * (2048LL * 1024LL);
    const int colt0 = tx * 256 + wn * 64;
#pragma unroll
    for (int mf = 0; mf < 4; ++mf) {
#pragma unroll
      for (int nj = 0; nj < 4; ++nj) {
        int col = colt0 + nj * 16 + r16;
#pragma unroll
        for (int rr = 0; rr < 4; ++rr) {
          int row = rowt0 + mf * 16 + kq * 4 + rr;
          Cb[(size_t)row * 1024 + col] = acc[mf][nj][rr];
        }
      }
    }
  }
}

__global__ __launch_bounds__(512, 4) void k_qkv(
    const short* __restrict__ A, const short* __restrict__ Bm,
    const float* __restrict__ bq, const float* __restrict__ bk,
    const float* __restrict__ bv, short* __restrict__ Qb,
    short* __restrict__ Kb, short* __restrict__ Vt) {
  gemm_body<0>(A, Bm, bq, bk, bv, Qb, Kb, Vt, nullptr, nullptr, 1.0f);
}

__global__ __launch_bounds__(512, 4) void k_scores(
    const short* __restrict__ Q, const short* __restrict__ K,
    short* __restrict__ Sb, float scale) {
  gemm_body<2>(Q, K, nullptr, nullptr, nullptr, nullptr, nullptr, nullptr,
               Sb, nullptr, scale);
}

__global__ __launch_bounds__(512, 4) void k_pv(
    const short* __restrict__ S, const short* __restrict__ Vt,
    float* __restrict__ O) {
  gemm_body<3>(S, Vt, nullptr, nullptr, nullptr, nullptr, nullptr, nullptr,
               nullptr, O, 1.0f);
}

extern "C" void kernel_launch(void* const* d_in, const int* in_sizes, int n_in,
                              void* d_out, int out_size, void* d_ws, size_t ws_size,
                              hipStream_t stream) {
  const float* x  = (const float*)d_in[0];
  const float* Wq = (const float*)d_in[1];
  const float* bq = (const float*)d_in[2];
  const float* Wk = (const float*)d_in[3];
  const float* bk = (const float*)d_in[4];
  const float* Wv = (const float*)d_in[5];
  const float* bv = (const float*)d_in[6];

  const int B = 4;
  const long long MB = 1LL << 20;

  char* ws = (char*)d_ws;
  short* Qb   = (short*)(ws + 0 * MB);   // 16 MB bf16 Q [8192,1024]
  short* Kb   = (short*)(ws + 16 * MB);  // 16 MB bf16 K
  short* Vt   = (short*)(ws + 32 * MB);  // 16 MB bf16 V^T [4][1024][2048]
  short* xb   = (short*)(ws + 48 * MB);  // 16 MB bf16 x     (dead after QKV)
  short* Wcat = (short*)(ws + 64 * MB);  // 6 MB  bf16 [Wq;Wk;Wv] (dead after QKV)
  short* Sb   = (short*)(ws + 48 * MB);  // 32 MB scores, reuses xb/Wcat

  // 1. fused casts
  cast_all<<<2048, 256, 0, stream>>>(x, Wq, Wk, Wv, xb, Wcat);

  // 2. fused QKV projection: [8192,3072] = xb @ Wcat^T ; 768 blocks
  k_qkv<<<768, 512, 0, stream>>>(xb, Wcat, bq, bk, bv, Qb, Kb, Vt);

  // 3. scores: per batch S = tril(Q K^T) / 32, 72 (128x256) tiles x 4 batches
  dim3 g2(72, 1, B);
  k_scores<<<g2, 512, 0, stream>>>(Qb, Kb, Sb, 0.03125f);

  // 4. PV: per batch O = S @ Vt^T, causal K-extent, longest-first
  dim3 g3(64, 1, B);
  k_pv<<<g3, 512, 0, stream>>>(Sb, Vt, (float*)d_out);
}